// Round 9
// baseline (68.669 us; speedup 1.0000x reference)
//
#include <hip/hip_runtime.h>

// SpikeLayer: per-pixel CDF over C=128 channels + S=128 searchsorted lookups.
// B=64, C=128, H=64, W=64, S=128. Output int32 channel indices [B,S,H,W].
//
// R8b: same as R8 (512B global granules: block = two adjacent H-rows, each
// thread owns a pixel pair via float2 loads; LDS rows stride-132 + skew
// ((q>>4)&7)*4 so row bases cover all 8 aligned bank starts). Only change:
// the int2 NT store is packed into a uint64_t — __builtin_nontemporal_store
// rejects HIP_vector_type pointers.

#define BB 64
#define CC 128
#define HH 64
#define WW 64
#define SS 128

constexpr int PADR   = 132;          // base row stride (dwords)
constexpr int PPB    = 128;          // pixels per block (two W-rows)
constexpr int GROUPS = 8;            // thread groups (channel & spike split)
constexpr int KPG    = CC / GROUPS;  // 16 channels per group
constexpr int SPG    = SS / GROUPS;  // 16 spikes per group

__device__ __forceinline__ int rowbase(int q) {
  // 132*q + 4*((q>>4)&7): rowbase mod 32 covers all aligned start banks
  // uniformly across a wave's 64 lanes (8 lanes per start position).
  return q * PADR + (((q >> 4) & 7) << 2);
}

__global__ __launch_bounds__(512, 4) void spike_kernel(
    const float* __restrict__ inp,   // [B,C,H,W]
    const float* __restrict__ rnd,   // [B,S,H,W]
    int* __restrict__ out) {         // [B,S,H,W]
  __shared__ float cdf[PPB * PADR + 32];   // 67712 B
  __shared__ float gA[GROUPS * 64];        // even-pixel group totals, 2 KB
  __shared__ float gB[GROUPS * 64];        // odd-pixel group totals, 2 KB

  const int t  = threadIdx.x;
  const int p2 = t & 63;    // pixel-pair index (covers pixels 2*p2, 2*p2+1)
  const int g  = t >> 6;    // group (0..7), wave-uniform
  const int bid = blockIdx.x;
  const int b   = bid >> 5; // batch image
  const int h2  = bid & 31; // row pair (rows 2*h2, 2*h2+1)
  const size_t HW2  = (size_t)(HH * WW) / 2;     // 2048 float2 per plane
  const size_t poff = (size_t)h2 * 64 + p2;      // float2 offset in plane

  // ---- issue both read streams up front (512B per wave-instruction) ----
  const float2* ip = (const float2*)inp + ((size_t)b * CC + g * KPG) * HW2 + poff;
  float2 x[KPG];
#pragma unroll
  for (int k = 0; k < KPG; ++k) x[k] = ip[k * HW2];

  const float2* rp = (const float2*)rnd + ((size_t)b * SS + g * SPG) * HW2 + poff;
  float2 rv[SPG];
#pragma unroll
  for (int s = 0; s < SPG; ++s) rv[s] = rp[s * HW2];
  __builtin_amdgcn_sched_barrier(0);

  // ---- phase 1: cumsum for both pixels of the pair ----
  float ax = 0.f, ay = 0.f;
  float2 vals[KPG];
#pragma unroll
  for (int k = 0; k < KPG; ++k) {
    ax += x[k].x; ay += x[k].y;
    vals[k].x = ax; vals[k].y = ay;
  }
  gA[g * 64 + p2] = ax;
  gB[g * 64 + p2] = ay;
  __syncthreads();

  // ---- phase 2: cross-group prefix + CDF writes (both pixels) ----
  float offx = 0.f, offy = 0.f, totx = 0.f, toty = 0.f;
#pragma unroll
  for (int gg = 0; gg < GROUPS; ++gg) {
    const float va = gA[gg * 64 + p2];
    const float vb = gB[gg * 64 + p2];
    totx += va; toty += vb;
    if (gg < g) { offx += va; offy += vb; }
  }

  const int rbA = rowbase(2 * p2);
  const int rbB = rowbase(2 * p2 + 1);
#pragma unroll
  for (int j = 0; j < KPG / 4; ++j) {
    float4 wa, wb;
    wa.x = vals[4 * j + 0].x + offx;  wb.x = vals[4 * j + 0].y + offy;
    wa.y = vals[4 * j + 1].x + offx;  wb.y = vals[4 * j + 1].y + offy;
    wa.z = vals[4 * j + 2].x + offx;  wb.z = vals[4 * j + 2].y + offy;
    wa.w = vals[4 * j + 3].x + offx;  wb.w = vals[4 * j + 3].y + offy;
    *(float4*)&cdf[rbA + g * KPG + 4 * j] = wa;
    *(float4*)&cdf[rbB + g * KPG + 4 * j] = wb;
  }
  __syncthreads();

  // ---- phase 3: register-cached top 4 levels for both pixels ----
  const int rb2[2] = {rbA, rbB};
  float T63[2], T31[2], T95[2], T15[2], T47[2], T79[2], T111[2];
  float T7[2], T23[2], T39[2], T55[2], T71[2], T87[2], T103[2], T119[2];
#pragma unroll
  for (int e = 0; e < 2; ++e) {
    const int rb = rb2[e];
    T63[e]  = cdf[rb + 63];
    T31[e]  = cdf[rb + 31];  T95[e]  = cdf[rb + 95];
    T15[e]  = cdf[rb + 15];  T47[e]  = cdf[rb + 47];
    T79[e]  = cdf[rb + 79];  T111[e] = cdf[rb + 111];
    T7[e]   = cdf[rb + 7];   T23[e]  = cdf[rb + 23];
    T39[e]  = cdf[rb + 39];  T55[e]  = cdf[rb + 55];
    T71[e]  = cdf[rb + 71];  T87[e]  = cdf[rb + 87];
    T103[e] = cdf[rb + 103]; T119[e] = cdf[rb + 119];
  }
  const float tot2[2] = {totx, toty};

  unsigned long long* op =
      (unsigned long long*)out + ((size_t)b * SS + g * SPG) * HW2 + poff;

#pragma unroll
  for (int s = 0; s < SPG; ++s) {
    int res[2];
#pragma unroll
    for (int e = 0; e < 2; ++e) {
      const float r = (e ? rv[s].y : rv[s].x) * tot2[e];
      const bool b1 = T63[e] < r;
      const float v2 = b1 ? T95[e] : T31[e];
      const bool b2 = v2 < r;
      const float t3a = b2 ? T47[e] : T15[e];
      const float t3b = b2 ? T111[e] : T79[e];
      const float v3 = b1 ? t3b : t3a;
      const bool b3 = v3 < r;
      const float t4a = b3 ? T23[e] : T7[e];
      const float t4b = b3 ? T55[e] : T39[e];
      const float t4c = b3 ? T87[e] : T71[e];
      const float t4d = b3 ? T119[e] : T103[e];
      const float u4a = b2 ? t4b : t4a;
      const float u4b = b2 ? t4d : t4c;
      const float v4 = b1 ? u4b : u4a;
      const bool b4 = v4 < r;
      const int idx = (b1 ? 64 : 0) + (b2 ? 32 : 0) + (b3 ? 16 : 0) + (b4 ? 8 : 0);
      const float4 ca = *(const float4*)&cdf[rb2[e] + idx];
      const float4 cb = *(const float4*)&cdf[rb2[e] + idx + 4];
      res[e] = idx + (ca.x < r) + (ca.y < r) + (ca.z < r) + (ca.w < r)
                   + (cb.x < r) + (cb.y < r) + (cb.z < r);
    }
    const unsigned long long packed =
        (unsigned long long)(unsigned)res[0] |
        ((unsigned long long)(unsigned)res[1] << 32);
    __builtin_nontemporal_store(packed, &op[s * HW2]);
  }
}

extern "C" void kernel_launch(void* const* d_in, const int* in_sizes, int n_in,
                              void* d_out, int out_size, void* d_ws, size_t ws_size,
                              hipStream_t stream) {
  const float* inp = (const float*)d_in[0];  // "input"         [B,C,H,W] f32
  const float* rnd = (const float*)d_in[1];  // "random_values" [B,S,H,W] f32
  int* out = (int*)d_out;                    // int32 indices   [B,S,H,W]
  (void)in_sizes; (void)n_in; (void)out_size; (void)d_ws; (void)ws_size;

  spike_kernel<<<dim3(BB * (HH / 2)), dim3(512), 0, stream>>>(inp, rnd, out);
}